// Round 4
// baseline (76.718 us; speedup 1.0000x reference)
//
#include <hip/hip_runtime.h>
#include <math.h>

// zc layout: [j2(6)][rb(192)][kko(16)] 1KB tiles of [r16(16)][w32(32)] bf16.
//   row = rb*16 + r16 (compact: h*6 + (m-2)), k-dim w = kko*32 + w32.
// dw layout: [kb(32)][kko(16)] 1KB tiles of [k16(16)][w32(32)] bf16; k = kb*16+k16.
// A wave-load of one tile: lane offset (l&15)*64B + (l>>4)*16B = contiguous 1KB.

typedef __attribute__((ext_vector_type(8))) __bf16 bf16x8;
typedef __attribute__((ext_vector_type(4))) float  f32x4;

__device__ __forceinline__ unsigned short f2bf(float f) {
  union { float f; unsigned u; } v; v.f = f;
  unsigned r = v.u + 0x7fffu + ((v.u >> 16) & 1u);   // RNE
  return (unsigned short)(r >> 16);
}
__device__ __forceinline__ float bf2f(unsigned short s) {
  union { unsigned u; float f; } v; v.u = ((unsigned)s) << 16;
  return v.f;
}

__device__ const float DBC[8][8] = {
  { 0.35355339f,  0.35355339f,  0.35355339f,  0.35355339f,  0.35355339f,  0.35355339f,  0.35355339f,  0.35355339f},
  { 0.49039264f,  0.41573481f,  0.27778512f,  0.09754516f, -0.09754516f, -0.27778512f, -0.41573481f, -0.49039264f},
  { 0.46193977f,  0.19134172f, -0.19134172f, -0.46193977f, -0.46193977f, -0.19134172f,  0.19134172f,  0.46193977f},
  { 0.41573481f, -0.09754516f, -0.49039264f, -0.27778512f,  0.27778512f,  0.49039264f,  0.09754516f, -0.41573481f},
  { 0.35355339f, -0.35355339f, -0.35355339f,  0.35355339f,  0.35355339f, -0.35355339f, -0.35355339f,  0.35355339f},
  { 0.27778512f, -0.49039264f,  0.09754516f,  0.41573481f, -0.41573481f, -0.09754516f,  0.49039264f, -0.27778512f},
  { 0.19134172f, -0.46193977f,  0.46193977f, -0.19134172f, -0.19134172f,  0.46193977f, -0.46193977f,  0.19134172f},
  { 0.09754516f, -0.27778512f,  0.41573481f, -0.49039264f,  0.49039264f, -0.41573481f,  0.27778512f, -0.09754516f}
};

// ---------------- 1) pack + dw build fused. grid (512, 2) x 256 threads.
__global__ __launch_bounds__(256) void pack_all(const float* __restrict__ x,
                                                unsigned short* __restrict__ zc,
                                                unsigned short* __restrict__ dwf) {
  const int h = blockIdx.x, t = threadIdx.x;

  // --- one Dw element per thread (262144 threads == 512*512 elements)
  {
    const int idx = (blockIdx.y * 512 + blockIdx.x) * 256 + t;
    const int k = idx >> 9, w = idx & 511;
    const int n = (k * (2 * w + 1)) & 2047;                 // exact integer angle reduction
    const float c = __cosf((float)n * 0.0030679615757712823f);  // pi/1024
    const float scale = (k == 0) ? 0.04419417382415922f : 0.0625f;
    dwf[(size_t)((((k >> 4) << 4) + (w >> 5)) << 9) + ((k & 15) << 5) + (w & 31)] =
        f2bf(c * scale);
  }

  // --- pack: q = floor(255x), Db rows m=2..7, scatter into fragment tiles
  const int c0 = blockIdx.y * 2048 + t * 8;   // this thread's 8 cols = one w, all j
  const float* xb = x + (size_t)(h * 8) * 4096 + c0;
  float q[8][8];
#pragma unroll
  for (int i = 0; i < 8; ++i) {
    float4 a = *reinterpret_cast<const float4*>(xb + (size_t)i * 4096);
    float4 b = *reinterpret_cast<const float4*>(xb + (size_t)i * 4096 + 4);
    q[i][0] = floorf(a.x * 255.0f); q[i][1] = floorf(a.y * 255.0f);
    q[i][2] = floorf(a.z * 255.0f); q[i][3] = floorf(a.w * 255.0f);
    q[i][4] = floorf(b.x * 255.0f); q[i][5] = floorf(b.y * 255.0f);
    q[i][6] = floorf(b.z * 255.0f); q[i][7] = floorf(b.w * 255.0f);
  }
  const int w0  = c0 >> 3;
  const int kko = w0 >> 5, w31 = w0 & 31;
#pragma unroll
  for (int m = 2; m < 8; ++m) {
    const int row = h * 6 + (m - 2);
    const size_t base = (size_t)(((row >> 4) << 4) + kko) * 512 + ((row & 15) << 5) + w31;
#pragma unroll
    for (int j = 2; j < 8; ++j) {
      float v = 0.0f;
#pragma unroll
      for (int i = 0; i < 8; ++i) v = fmaf(DBC[m][i], q[i][j], v);
      zc[(size_t)(j - 2) * 1572864 + base] = f2bf(v);   // j2 plane = 192*16*512 elems
    }
  }
}

// ---------------- 2) fused barrier-free register GEMM + interleave epilogue
// Block (mt 0..31, nt 0..15): out rows [mt*128,+128), cols [nt*256,+256).
// 6 waves; wave wv owns j = wv+2: M=96 (6 frags), N=32 (2 frags), K=512, 16 steps.
__global__ __launch_bounds__(384, 3) void fused_dct(const unsigned short* __restrict__ zc,
                                                    const unsigned short* __restrict__ dwf,
                                                    float* __restrict__ out) {
  const int bid = blockIdx.x;     // bid = nt*32+mt -> XCD = mt%8: same-mt blocks share L2
  const int mt  = bid & 31;
  const int nt  = bid >> 5;

  __shared__ unsigned short Obuf[6 * 3264];   // 6 planes x [96][34] bf16, 38.25 KB

  const int tid  = threadIdx.x;
  const int lane = tid & 63;
  const int wv   = tid >> 6;        // 0..5 = j-2
  const int l15  = lane & 15;
  const int loff = (l15 << 5) + ((lane >> 4) << 3);   // elem offset inside a 1KB tile

  const unsigned short* Aw = zc + (size_t)(wv * 192 + mt * 6) * 8192 + loff;
  const unsigned short* Bw = dwf + (size_t)(nt * 2) * 8192 + loff;

  f32x4 acc[6][2] = {};

#define LD(AS, BS, kk)                                                              \
  do {                                                                              \
    _Pragma("unroll")                                                               \
    for (int mf_ = 0; mf_ < 6; ++mf_)                                               \
      AS[mf_] = *reinterpret_cast<const bf16x8*>(Aw + mf_ * 8192 + (kk) * 512);     \
    BS[0] = *reinterpret_cast<const bf16x8*>(Bw + (kk) * 512);                      \
    BS[1] = *reinterpret_cast<const bf16x8*>(Bw + 8192 + (kk) * 512);               \
  } while (0)

#define MM(AS, BS)                                                                  \
  do {                                                                              \
    _Pragma("unroll")                                                               \
    for (int mf_ = 0; mf_ < 6; ++mf_) {                                             \
      acc[mf_][0] = __builtin_amdgcn_mfma_f32_16x16x32_bf16(AS[mf_], BS[0], acc[mf_][0], 0, 0, 0); \
      acc[mf_][1] = __builtin_amdgcn_mfma_f32_16x16x32_bf16(AS[mf_], BS[1], acc[mf_][1], 0, 0, 0); \
    }                                                                               \
  } while (0)

  bf16x8 a0[6], b0[2], a1[6], b1[2];
  LD(a0, b0, 0);
#pragma unroll
  for (int tt = 0; tt < 16; tt += 2) {     // ping-pong, fully static after unroll
    if (tt + 1 < 16) LD(a1, b1, tt + 1);
    MM(a0, b0);
    if (tt + 2 < 16) LD(a0, b0, tt + 2);
    MM(a1, b1);
  }
#undef LD
#undef MM

  // ---- C -> Obuf (plane wv), pitch 34 to spread banks
  unsigned short* Ob = Obuf + wv * 3264;
#pragma unroll
  for (int mf = 0; mf < 6; ++mf)
#pragma unroll
    for (int nf = 0; nf < 2; ++nf)
#pragma unroll
      for (int p = 0; p < 4; ++p)
        Ob[(mf * 16 + (lane >> 4) * 4 + p) * 34 + nf * 16 + l15] = f2bf(acc[mf][nf][p]);
  __syncthreads();

  // ---- epilogue: 128 rows x 256 f32 cols, coalesced f32x4 incl. mask zeros
  float* outb = out + (size_t)(mt * 128) * 4096 + nt * 256;
  for (int v = tid; v < 8192; v += 384) {
    const int row128 = v >> 6;
    const int c4 = (v & 63) << 2;
    f32x4 val = {0.0f, 0.0f, 0.0f, 0.0f};
    const int m = row128 & 7;
    if (m >= 2) {
      const int row96 = (row128 >> 3) * 6 + (m - 2);
      const int kk = c4 >> 3, jb = c4 & 4;
#pragma unroll
      for (int e = 0; e < 4; ++e) {
        const int j = jb + e;
        if (j >= 2)
          val[e] = bf2f(Obuf[(j - 2) * 3264 + row96 * 34 + kk]);
      }
    }
    *reinterpret_cast<f32x4*>(outb + (size_t)row128 * 4096 + c4) = val;
  }
}

extern "C" void kernel_launch(void* const* d_in, const int* in_sizes, int n_in,
                              void* d_out, int out_size, void* d_ws, size_t ws_size,
                              hipStream_t stream) {
  const float* x = (const float*)d_in[0];
  float* out = (float*)d_out;
  char* ws = (char*)d_ws;

  unsigned short* dwf = (unsigned short*)ws;             // 512 KB
  unsigned short* zc  = (unsigned short*)(ws + 524288);  // 18.87 MB

  pack_all<<<dim3(512, 2), 256, 0, stream>>>(x, zc, dwf);
  fused_dct<<<512, 384, 0, stream>>>(zc, dwf, out);
}

// Round 5
// 49.645 us; speedup vs baseline: 1.5453x; 1.5453x over previous
//
#include <hip/hip_runtime.h>
#include <math.h>

// zc layout: [(j2*16 + kko)][3072 rows][32 w] bf16, chunk-swizzled: logical 8-elem
//   chunk g of row r stored at chunk (g ^ ((r>>1)&3)). Plane = 98304 elems.
// dw layout: [kko(16)][512 k][32 w] bf16, same swizzle keyed on k.
#define ZSLAB 98304
#define DSLAB 16384

typedef __attribute__((ext_vector_type(8))) __bf16 bf16x8;
typedef __attribute__((ext_vector_type(4))) float  f32x4;

__device__ __forceinline__ unsigned short f2bf(float f) {
  union { float f; unsigned u; } v; v.f = f;
  unsigned r = v.u + 0x7fffu + ((v.u >> 16) & 1u);   // RNE
  return (unsigned short)(r >> 16);
}
__device__ __forceinline__ float bf2f(unsigned short s) {
  union { unsigned u; float f; } v; v.u = ((unsigned)s) << 16;
  return v.f;
}

__device__ const float DBC[8][8] = {
  { 0.35355339f,  0.35355339f,  0.35355339f,  0.35355339f,  0.35355339f,  0.35355339f,  0.35355339f,  0.35355339f},
  { 0.49039264f,  0.41573481f,  0.27778512f,  0.09754516f, -0.09754516f, -0.27778512f, -0.41573481f, -0.49039264f},
  { 0.46193977f,  0.19134172f, -0.19134172f, -0.46193977f, -0.46193977f, -0.19134172f,  0.19134172f,  0.46193977f},
  { 0.41573481f, -0.09754516f, -0.49039264f, -0.27778512f,  0.27778512f,  0.49039264f,  0.09754516f, -0.41573481f},
  { 0.35355339f, -0.35355339f, -0.35355339f,  0.35355339f,  0.35355339f, -0.35355339f, -0.35355339f,  0.35355339f},
  { 0.27778512f, -0.49039264f,  0.09754516f,  0.41573481f, -0.41573481f, -0.09754516f,  0.49039264f, -0.27778512f},
  { 0.19134172f, -0.46193977f,  0.46193977f, -0.19134172f, -0.19134172f,  0.46193977f, -0.46193977f,  0.19134172f},
  { 0.09754516f, -0.27778512f,  0.41573481f, -0.49039264f,  0.49039264f, -0.41573481f,  0.27778512f, -0.09754516f}
};

// ---------------- 1) pack + dw build fused. grid (512, 2) x 256 threads.
__global__ __launch_bounds__(256) void pack_all(const float* __restrict__ x,
                                                unsigned short* __restrict__ zc,
                                                unsigned short* __restrict__ dwf) {
  const int h = blockIdx.x, t = threadIdx.x;

  // --- one Dw element per thread (262144 threads == 512*512 elements)
  {
    const int idx = (blockIdx.y * 512 + blockIdx.x) * 256 + t;
    const int k = idx >> 9, w = idx & 511;
    const int n = (k * (2 * w + 1)) & 2047;                     // exact angle reduction
    const float c = __cosf((float)n * 0.0030679615757712823f);  // pi/1024
    const float scale = (k == 0) ? 0.04419417382415922f : 0.0625f;
    const int kko = w >> 5, g = (w >> 3) & 3, e = w & 7, s = (k >> 1) & 3;
    dwf[(size_t)kko * DSLAB + k * 32 + ((g ^ s) << 3) + e] = f2bf(c * scale);
  }

  // --- pack: q = floor(255x), Db rows m=2..7, emit swizzled planes
  const int c0 = blockIdx.y * 2048 + t * 8;   // this thread's 8 cols = one w, all j
  const float* xb = x + (size_t)(h * 8) * 4096 + c0;
  float q[8][8];
#pragma unroll
  for (int i = 0; i < 8; ++i) {
    float4 a = *reinterpret_cast<const float4*>(xb + (size_t)i * 4096);
    float4 b = *reinterpret_cast<const float4*>(xb + (size_t)i * 4096 + 4);
    q[i][0] = floorf(a.x * 255.0f); q[i][1] = floorf(a.y * 255.0f);
    q[i][2] = floorf(a.z * 255.0f); q[i][3] = floorf(a.w * 255.0f);
    q[i][4] = floorf(b.x * 255.0f); q[i][5] = floorf(b.y * 255.0f);
    q[i][6] = floorf(b.z * 255.0f); q[i][7] = floorf(b.w * 255.0f);
  }
  const int w0 = c0 >> 3;
  const int kko = w0 >> 5, g = (w0 >> 3) & 3, e = w0 & 7;
#pragma unroll
  for (int m = 2; m < 8; ++m) {
    const int row = h * 6 + (m - 2);
    const int s = (row >> 1) & 3;
    const size_t base = (size_t)row * 32 + ((g ^ s) << 3) + e;
#pragma unroll
    for (int j = 2; j < 8; ++j) {
      float v = 0.0f;
#pragma unroll
      for (int i = 0; i < 8; ++i) v = fmaf(DBC[m][i], q[i][j], v);
      zc[(size_t)((j - 2) * 16 + kko) * ZSLAB + base] = f2bf(v);
    }
  }
}

// ---------------- 2) fused batched-GEMM + interleave, 4 blocks/CU
// Block (mt 0..63, nt 0..15): out rows [mt*64,+64), cols [nt*256,+256).
// 6 waves, wave wv owns j = wv+2: M=48 (3 frags), N=32 (2 frags), K=512, BK=32.
__device__ __forceinline__ void gload16(const unsigned short* g, unsigned short* l) {
  __builtin_amdgcn_global_load_lds(
      (__attribute__((address_space(1))) void*)(g),
      (__attribute__((address_space(3))) void*)(l),
      16, 0, 0);
}

__global__ __launch_bounds__(384, 6) void fused_dct(const unsigned short* __restrict__ zc,
                                                    const unsigned short* __restrict__ dwf,
                                                    float* __restrict__ out) {
  const int bid = blockIdx.x;     // bid = nt*64+mt -> XCD = mt%8: same-mt blocks share L2
  const int mt  = bid & 63;
  const int nt  = bid >> 6;

  // LDS map (40960 B exactly -> 4 blocks/CU):
  //   [A0: 0..18431][B0: 18432..20479][A1: 20480..38911][B1: 38912..40959]
  //   Obuf (6*48*34*2 = 19584 B) aliases {A0,B0}; final iter (t=15) uses {A1,B1}.
  __shared__ __align__(16) unsigned char SM[40960];
  unsigned short* Obuf = (unsigned short*)SM;

  const int tid  = threadIdx.x;
  const int lane = tid & 63;
  const int wv   = tid >> 6;        // 0..5 = j-2
  const int l15  = lane & 15;
  const int hlf  = (tid >= 192) ? 1 : 0;     // wave-uniform
  const int rem  = tid - hlf * 192;

  f32x4 acc[3][2] = {};

  // A per step: 6j x 48r x 32w = 18432 B = 3 gload16/thread; B: 2048 B (waves 0,1).
#define STAGE(buf, kkos)                                                             \
  do {                                                                               \
    unsigned short* As_ = (unsigned short*)(SM + (buf) * 20480);                     \
    _Pragma("unroll")                                                                \
    for (int q_ = 0; q_ < 3; ++q_) {                                                 \
      const int j2_ = 2 * q_ + hlf;                                                  \
      gload16(zc + (size_t)(j2_ * 16 + (kkos)) * ZSLAB + mt * 1536 + rem * 8,        \
              As_ + (q_ * 384 + tid) * 8);                                           \
    }                                                                                \
    if (tid < 128)                                                                   \
      gload16(dwf + (size_t)(kkos) * DSLAB + nt * 1024 + tid * 8,                    \
              (unsigned short*)(SM + 18432 + (buf) * 20480) + tid * 8);              \
  } while (0)

  STAGE(0, 0);
  __syncthreads();
  for (int t = 0; t < 16; ++t) {
    const int cur = t & 1;
    if (t < 15) STAGE(cur ^ 1, t + 1);      // issue-early: in flight across compute
    const unsigned short* Ap = (const unsigned short*)(SM + cur * 20480) + wv * 1536;
    const unsigned short* Bp = (const unsigned short*)(SM + 18432 + cur * 20480);
    bf16x8 bfr[2];
#pragma unroll
    for (int nf = 0; nf < 2; ++nf) {
      const int r = nf * 16 + l15;
      bfr[nf] = *reinterpret_cast<const bf16x8*>(
          Bp + r * 32 + (((lane >> 4) ^ ((r >> 1) & 3)) << 3));
    }
#pragma unroll
    for (int mf = 0; mf < 3; ++mf) {
      const int r = mf * 16 + l15;
      const bf16x8 afr = *reinterpret_cast<const bf16x8*>(
          Ap + r * 32 + (((lane >> 4) ^ ((r >> 1) & 3)) << 3));
      acc[mf][0] = __builtin_amdgcn_mfma_f32_16x16x32_bf16(afr, bfr[0], acc[mf][0], 0, 0, 0);
      acc[mf][1] = __builtin_amdgcn_mfma_f32_16x16x32_bf16(afr, bfr[1], acc[mf][1], 0, 0, 0);
    }
    __syncthreads();                        // drains stage t+1; gates buffer reuse
  }
#undef STAGE

  // ---- C -> Obuf (plane wv = j-2), 48 rows, pitch 34 (aliases A0/B0 only)
  unsigned short* Ob = Obuf + wv * 1632;
#pragma unroll
  for (int mf = 0; mf < 3; ++mf)
#pragma unroll
    for (int nf = 0; nf < 2; ++nf)
#pragma unroll
      for (int p = 0; p < 4; ++p)
        Ob[(mf * 16 + (lane >> 4) * 4 + p) * 34 + nf * 16 + l15] = f2bf(acc[mf][nf][p]);
  __syncthreads();

  // ---- epilogue: 64 rows x 256 f32 cols, coalesced f32x4 incl. mask zeros
  float* outb = out + (size_t)(mt * 64) * 4096 + nt * 256;
  for (int v = tid; v < 4096; v += 384) {
    const int row64 = v >> 6;
    const int c4 = (v & 63) << 2;
    f32x4 val = {0.0f, 0.0f, 0.0f, 0.0f};
    const int m = row64 & 7;
    if (m >= 2) {
      const int row48 = (row64 >> 3) * 6 + (m - 2);
      const int kk = c4 >> 3, jb = c4 & 4;
#pragma unroll
      for (int e = 0; e < 4; ++e) {
        const int j = jb + e;
        if (j >= 2)
          val[e] = bf2f(Obuf[(j - 2) * 1632 + row48 * 34 + kk]);
      }
    }
    *reinterpret_cast<f32x4*>(outb + (size_t)row64 * 4096 + c4) = val;
  }
}

extern "C" void kernel_launch(void* const* d_in, const int* in_sizes, int n_in,
                              void* d_out, int out_size, void* d_ws, size_t ws_size,
                              hipStream_t stream) {
  const float* x = (const float*)d_in[0];
  float* out = (float*)d_out;
  char* ws = (char*)d_ws;

  unsigned short* dwf = (unsigned short*)ws;             // 512 KB
  unsigned short* zc  = (unsigned short*)(ws + 524288);  // 18.87 MB

  pack_all<<<dim3(512, 2), 256, 0, stream>>>(x, zc, dwf);
  fused_dct<<<1024, 384, 0, stream>>>(zc, dwf, out);
}

// Round 6
// 46.854 us; speedup vs baseline: 1.6374x; 1.0596x over previous
//
#include <hip/hip_runtime.h>
#include <math.h>

// zc layout: [(j2*16 + kko)][3072 rows][32 w] bf16, chunk-swizzled: logical 8-elem
//   chunk g of row r stored at chunk (g ^ ((r>>1)&3)). Plane = 98304 elems.
// dw layout: [kko(16)][512 k][32 w] bf16, same swizzle keyed on k.
#define ZSLAB 98304
#define DSLAB 16384

typedef __attribute__((ext_vector_type(8))) __bf16 bf16x8;
typedef __attribute__((ext_vector_type(4))) float  f32x4;

__device__ __forceinline__ unsigned short f2bf(float f) {
  union { float f; unsigned u; } v; v.f = f;
  unsigned r = v.u + 0x7fffu + ((v.u >> 16) & 1u);   // RNE
  return (unsigned short)(r >> 16);
}
__device__ __forceinline__ float bf2f(unsigned short s) {
  union { unsigned u; float f; } v; v.u = ((unsigned)s) << 16;
  return v.f;
}

__device__ const float DBC[8][8] = {
  { 0.35355339f,  0.35355339f,  0.35355339f,  0.35355339f,  0.35355339f,  0.35355339f,  0.35355339f,  0.35355339f},
  { 0.49039264f,  0.41573481f,  0.27778512f,  0.09754516f, -0.09754516f, -0.27778512f, -0.41573481f, -0.49039264f},
  { 0.46193977f,  0.19134172f, -0.19134172f, -0.46193977f, -0.46193977f, -0.19134172f,  0.19134172f,  0.46193977f},
  { 0.41573481f, -0.09754516f, -0.49039264f, -0.27778512f,  0.27778512f,  0.49039264f,  0.09754516f, -0.41573481f},
  { 0.35355339f, -0.35355339f, -0.35355339f,  0.35355339f,  0.35355339f, -0.35355339f, -0.35355339f,  0.35355339f},
  { 0.27778512f, -0.49039264f,  0.09754516f,  0.41573481f, -0.41573481f, -0.09754516f,  0.49039264f, -0.27778512f},
  { 0.19134172f, -0.46193977f,  0.46193977f, -0.19134172f, -0.19134172f,  0.46193977f, -0.46193977f,  0.19134172f},
  { 0.09754516f, -0.27778512f,  0.41573481f, -0.49039264f,  0.49039264f, -0.41573481f,  0.27778512f, -0.09754516f}
};

// ---------------- 1) pack + dw build fused. grid (512, 2) x 256 threads.
__global__ __launch_bounds__(256) void pack_all(const float* __restrict__ x,
                                                unsigned short* __restrict__ zc,
                                                unsigned short* __restrict__ dwf) {
  const int h = blockIdx.x, t = threadIdx.x;

  // --- one Dw element per thread (262144 threads == 512*512 elements)
  {
    const int idx = (blockIdx.y * 512 + blockIdx.x) * 256 + t;
    const int k = idx >> 9, w = idx & 511;
    const int n = (k * (2 * w + 1)) & 2047;                     // exact angle reduction
    const float c = __cosf((float)n * 0.0030679615757712823f);  // pi/1024
    const float scale = (k == 0) ? 0.04419417382415922f : 0.0625f;
    const int kko = w >> 5, g = (w >> 3) & 3, e = w & 7, s = (k >> 1) & 3;
    dwf[(size_t)kko * DSLAB + k * 32 + ((g ^ s) << 3) + e] = f2bf(c * scale);
  }

  // --- pack: q = floor(255x), Db rows m=2..7, emit swizzled planes
  const int c0 = blockIdx.y * 2048 + t * 8;   // this thread's 8 cols = one w, all j
  const float* xb = x + (size_t)(h * 8) * 4096 + c0;
  float q[8][8];
#pragma unroll
  for (int i = 0; i < 8; ++i) {
    float4 a = *reinterpret_cast<const float4*>(xb + (size_t)i * 4096);
    float4 b = *reinterpret_cast<const float4*>(xb + (size_t)i * 4096 + 4);
    q[i][0] = floorf(a.x * 255.0f); q[i][1] = floorf(a.y * 255.0f);
    q[i][2] = floorf(a.z * 255.0f); q[i][3] = floorf(a.w * 255.0f);
    q[i][4] = floorf(b.x * 255.0f); q[i][5] = floorf(b.y * 255.0f);
    q[i][6] = floorf(b.z * 255.0f); q[i][7] = floorf(b.w * 255.0f);
  }
  const int w0 = c0 >> 3;
  const int kko = w0 >> 5, g = (w0 >> 3) & 3, e = w0 & 7;
#pragma unroll
  for (int m = 2; m < 8; ++m) {
    const int row = h * 6 + (m - 2);
    const int s = (row >> 1) & 3;
    const size_t base = (size_t)row * 32 + ((g ^ s) << 3) + e;
#pragma unroll
    for (int j = 2; j < 8; ++j) {
      float v = 0.0f;
#pragma unroll
      for (int i = 0; i < 8; ++i) v = fmaf(DBC[m][i], q[i][j], v);
      zc[(size_t)((j - 2) * 16 + kko) * ZSLAB + base] = f2bf(v);
    }
  }
}

// ---------------- 2) fused batched-GEMM + interleave, 4 blocks/CU, counted-vmcnt pipe
// Block (mt 0..63, nt 0..15): out rows [mt*64,+64), cols [nt*256,+256).
// 6 waves, wave wv owns j = wv+2: M=48 (3 frags), N=32 (2 frags), K=512, BK=32.
__device__ __forceinline__ void gload16(const unsigned short* g, unsigned short* l) {
  __builtin_amdgcn_global_load_lds(
      (__attribute__((address_space(1))) void*)(g),
      (__attribute__((address_space(3))) void*)(l),
      16, 0, 0);
}

__global__ __launch_bounds__(384, 6) void fused_dct(const unsigned short* __restrict__ zc,
                                                    const unsigned short* __restrict__ dwf,
                                                    float* __restrict__ out) {
  const int bid = blockIdx.x;     // bid = nt*64+mt -> XCD = mt%8: same-mt blocks share L2
  const int mt  = bid & 63;
  const int nt  = bid >> 6;

  // LDS map (40960 B -> 4 blocks/CU):
  //   [A0: 0..18431][B0: 18432..20479][A1: 20480..38911][B1: 38912..40959]
  //   Obuf (19584 B) aliases {A0,B0}; final compute (t=15) reads {A1,B1}.
  __shared__ __align__(16) unsigned char SM[40960];
  unsigned short* Obuf = (unsigned short*)SM;

  const int tid  = threadIdx.x;
  const int lane = tid & 63;
  const int wv   = tid >> 6;        // 0..5 = j-2
  const int l15  = lane & 15;
  const int hlf  = (tid >= 192) ? 1 : 0;     // wave-uniform
  const int rem  = tid - hlf * 192;

  f32x4 acc[3][2] = {};

  // Every thread issues EXACTLY 4 gload16 per stage (3 A + 1 B) so vmcnt counts are
  // wave-uniform. B (2 KB) is covered by tid&127; waves 2..5 duplicate-write identical
  // bytes to the same LDS dest (benign; each wave's own vmcnt covers its copy).
#define STAGE(buf, kkos)                                                             \
  do {                                                                               \
    unsigned short* As_ = (unsigned short*)(SM + (buf) * 20480);                     \
    _Pragma("unroll")                                                                \
    for (int q_ = 0; q_ < 3; ++q_) {                                                 \
      const int j2_ = 2 * q_ + hlf;                                                  \
      gload16(zc + (size_t)(j2_ * 16 + (kkos)) * ZSLAB + mt * 1536 + rem * 8,        \
              As_ + (q_ * 384 + tid) * 8);                                           \
    }                                                                                \
    gload16(dwf + (size_t)(kkos) * DSLAB + nt * 1024 + (tid & 127) * 8,              \
            (unsigned short*)(SM + 18432 + (buf) * 20480) + (tid & 127) * 8);        \
  } while (0)

#define COMPUTE(cur)                                                                 \
  do {                                                                               \
    const unsigned short* Ap = (const unsigned short*)(SM + (cur) * 20480) + wv * 1536; \
    const unsigned short* Bp = (const unsigned short*)(SM + 18432 + (cur) * 20480);  \
    bf16x8 bfr[2];                                                                   \
    _Pragma("unroll")                                                                \
    for (int nf = 0; nf < 2; ++nf) {                                                 \
      const int r_ = nf * 16 + l15;                                                  \
      bfr[nf] = *reinterpret_cast<const bf16x8*>(                                    \
          Bp + r_ * 32 + (((lane >> 4) ^ ((r_ >> 1) & 3)) << 3));                    \
    }                                                                                \
    _Pragma("unroll")                                                                \
    for (int mf = 0; mf < 3; ++mf) {                                                 \
      const int r_ = mf * 16 + l15;                                                  \
      const bf16x8 afr = *reinterpret_cast<const bf16x8*>(                           \
          Ap + r_ * 32 + (((lane >> 4) ^ ((r_ >> 1) & 3)) << 3));                    \
      acc[mf][0] = __builtin_amdgcn_mfma_f32_16x16x32_bf16(afr, bfr[0], acc[mf][0], 0, 0, 0); \
      acc[mf][1] = __builtin_amdgcn_mfma_f32_16x16x32_bf16(afr, bfr[1], acc[mf][1], 0, 0, 0); \
    }                                                                                \
  } while (0)

  STAGE(0, 0);
  STAGE(1, 1);
  // Main loop t=0..14: stage t's 4 loads done (4 of stage t+1 still in flight -> vmcnt(4)).
  for (int t = 0; t < 15; ++t) {
    const int cur = t & 1;
    asm volatile("s_waitcnt vmcnt(4)" ::: "memory");
    __builtin_amdgcn_s_barrier();            // all waves' stage-t writes landed
    COMPUTE(cur);
    asm volatile("s_waitcnt lgkmcnt(0)" ::: "memory");
    __builtin_amdgcn_s_barrier();            // all waves done READING buf[cur]
    if (t < 14) STAGE(cur, t + 2);           // overwrite buf[cur] with stage t+2
  }
  // t = 15 (last stage): drain remaining loads fully.
  asm volatile("s_waitcnt vmcnt(0)" ::: "memory");
  __builtin_amdgcn_s_barrier();
  COMPUTE(1);
#undef STAGE
#undef COMPUTE

  // ---- C -> Obuf (plane wv = j-2), 48 rows, pitch 34 (aliases A0/B0 region only;
  // concurrent t=15 readers use A1/B1 -> disjoint).
  unsigned short* Ob = Obuf + wv * 1632;
#pragma unroll
  for (int mf = 0; mf < 3; ++mf)
#pragma unroll
    for (int nf = 0; nf < 2; ++nf)
#pragma unroll
      for (int p = 0; p < 4; ++p)
        Ob[(mf * 16 + (lane >> 4) * 4 + p) * 34 + nf * 16 + l15] = f2bf(acc[mf][nf][p]);
  __syncthreads();

  // ---- epilogue: 64 rows x 256 f32 cols, coalesced f32x4 incl. mask zeros
  float* outb = out + (size_t)(mt * 64) * 4096 + nt * 256;
  for (int v = tid; v < 4096; v += 384) {
    const int row64 = v >> 6;
    const int c4 = (v & 63) << 2;
    f32x4 val = {0.0f, 0.0f, 0.0f, 0.0f};
    const int m = row64 & 7;
    if (m >= 2) {
      const int row48 = (row64 >> 3) * 6 + (m - 2);
      const int kk = c4 >> 3, jb = c4 & 4;
#pragma unroll
      for (int e = 0; e < 4; ++e) {
        const int j = jb + e;
        if (j >= 2)
          val[e] = bf2f(Obuf[(j - 2) * 1632 + row48 * 34 + kk]);
      }
    }
    *reinterpret_cast<f32x4*>(outb + (size_t)row64 * 4096 + c4) = val;
  }
}

extern "C" void kernel_launch(void* const* d_in, const int* in_sizes, int n_in,
                              void* d_out, int out_size, void* d_ws, size_t ws_size,
                              hipStream_t stream) {
  const float* x = (const float*)d_in[0];
  float* out = (float*)d_out;
  char* ws = (char*)d_ws;

  unsigned short* dwf = (unsigned short*)ws;             // 512 KB
  unsigned short* zc  = (unsigned short*)(ws + 524288);  // 18.87 MB

  pack_all<<<dim3(512, 2), 256, 0, stream>>>(x, zc, dwf);
  fused_dct<<<1024, 384, 0, stream>>>(zc, dwf, out);
}